// Round 1
// 2789.560 us; speedup vs baseline: 1.2008x; 1.2008x over previous
//
#include <hip/hip_runtime.h>

// Problem constants (from setup_inputs): B=4, L=32, C=16, H=192, W=192
#define BB 4
#define LL 32
#define CC 16
#define HH 192
#define WW 192
#define HW (HH * WW)            // 36864
#define CHW (CC * HW)           // 589824
#define IMG_ELEMS ((size_t)BB * LL * CHW)      // 75,497,472
#define FLW_ELEMS ((size_t)BB * LL * 2 * HW)   // 9,437,184
#define TILES 144               // 3 across (64 wide) x 48 down (4 tall)
#define NXCD 8

// Location rule: when step s runs, slice u's latest copy lives at dst(q) with
// q = min(s/2, msb(u)); q==0 -> original input.
// Image dsts:  dst(1)=buf0, dst(2)=out, dst(4)=buf0, dst(8)=out, dst(16)=out
// Flow dsts:   dst(1)=fb0,  dst(2)=fb1, dst(4)=fb0,  dst(8)=fb1
__device__ __forceinline__ const float* sel3(int u, int shalf,
                                             const float* pin,
                                             const float* pa,   // q in {1,4}
                                             const float* pb) { // q in {2,8,16}
  int q = (u > 0) ? (1 << (31 - __builtin_clz((unsigned)u))) : 0;
  q = q < shalf ? q : shalf;
  if (q == 0) return pin;
  return (q == 1 || q == 4) ? pa : pb;
}

__global__ __launch_bounds__(256) void pscan_step(
    const float* __restrict__ img_in, const float* __restrict__ img_b0,
    const float* __restrict__ img_out_r,
    const float* __restrict__ flow_in, const float* __restrict__ flow_b0,
    const float* __restrict__ flow_b1,
    float* __restrict__ img_dst, float* __restrict__ flow_dst,
    int s, int write_flow, int pairs_per_xcd, int total_pairs, int ntt) {
  // Match the numpy f32 reference rounding-for-rounding: no FMA contraction.
  // (The x-wrap seam is discontinuous; 1-ULP drift flips samples across it.)
#pragma clang fp contract(off)
  // XCD-affinity decode: consecutive blockIdx.x round-robin across the 8 XCDs,
  // so blocks with equal (blockIdx.x % 8) share one XCD's L2. Give each XCD a
  // contiguous chunk of (b,t) pairs and keep a pair's 144 tiles contiguous in
  // that XCD's queue -> gather-halo lines dedup in L2 instead of being
  // refetched per-XCD.
  const int l = blockIdx.x;
  const int xcd = l & (NXCD - 1);
  const int j = l >> 3;
  const int pair = xcd * pairs_per_xcd + j / TILES;
  if (pair >= total_pairs) return;
  const int tile = j % TILES;
  const int b = pair / ntt;          // pairs ordered (b, t)-contiguous
  const int t = pair % ntt + s;      // t in [s, L)
  const int u = t - s;               // source slice
  const int w = (tile % 3) * 64 + threadIdx.x;
  const int h = (tile / 3) * 4 + threadIdx.y;
  const int shalf = s >> 1;

  const float* fcur = sel3(t, shalf, flow_in, flow_b0, flow_b1);
  const float* fprv = sel3(u, shalf, flow_in, flow_b0, flow_b1);
  const float* icur = sel3(t, shalf, img_in, img_b0, img_out_r);
  const float* iprv = sel3(u, shalf, img_in, img_b0, img_out_r);

  const int p = h * WW + w;

  // current flow at (b,t,:,h,w) — streamed once, keep out of L2
  const size_t fcbase = ((size_t)(b * LL + t) * 2) * HW;
  const float fcx = __builtin_nontemporal_load(fcur + fcbase + p);
  const float fcy = __builtin_nontemporal_load(fcur + fcbase + HW + p);

  // warp grid (pixel-center base grid + flow), wrap x into [-1,1)
  // gx = (w+0.5)*(2/W) - 1; fx = gx + flow_x  (exact reference op order)
  const float gx = (w + 0.5f) * (2.0f / WW) - 1.0f;
  const float gy = (h + 0.5f) * (2.0f / HH) - 1.0f;
  float fx = gx + fcx;
  float fy = gy + fcy;
  // np.remainder(fx+1, 2) - 1
  float r = fmodf(fx + 1.0f, 2.0f);
  if (r < 0.0f) r += 2.0f;
  fx = r - 1.0f;

  // bilinear, align_corners=False, zeros padding
  const float ix = (fx + 1.0f) * 0.5f * WW - 0.5f;
  const float iy = (fy + 1.0f) * 0.5f * HH - 0.5f;
  const float x0f = floorf(ix), y0f = floorf(iy);
  const float wx1 = ix - x0f, wy1 = iy - y0f;
  const float wx0 = 1.0f - wx1, wy0 = 1.0f - wy1;
  const int x0 = (int)x0f, y0 = (int)y0f;
  const int x1 = x0 + 1, y1 = y0 + 1;
  const bool vx0 = (x0 >= 0) & (x0 < WW), vx1 = (x1 >= 0) & (x1 < WW);
  const bool vy0 = (y0 >= 0) & (y0 < HH), vy1 = (y1 >= 0) & (y1 < HH);
  const int cx0 = min(max(x0, 0), WW - 1), cx1 = min(max(x1, 0), WW - 1);
  const int cy0 = min(max(y0, 0), HH - 1), cy1 = min(max(y1, 0), HH - 1);
  // weight * valid is exact (valid is 0.0 or 1.0), so this matches
  // (v*valid)*w of the reference rounding-for-rounding.
  const float w00 = wy0 * wx0 * ((vy0 && vx0) ? 1.0f : 0.0f);
  const float w01 = wy0 * wx1 * ((vy0 && vx1) ? 1.0f : 0.0f);
  const float w10 = wy1 * wx0 * ((vy1 && vx0) ? 1.0f : 0.0f);
  const float w11 = wy1 * wx1 * ((vy1 && vx1) ? 1.0f : 0.0f);
  const int i00 = cy0 * WW + cx0, i01 = cy0 * WW + cx1;
  const int i10 = cy1 * WW + cx0, i11 = cy1 * WW + cx1;

  if (write_flow) {
    const float* fp0 = fprv + ((size_t)(b * LL + u) * 2) * HW;
    const float* fp1 = fp0 + HW;
    const float s0 = w00 * fp0[i00] + w01 * fp0[i01] + w10 * fp0[i10] + w11 * fp0[i11];
    const float s1 = w00 * fp1[i00] + w01 * fp1[i01] + w10 * fp1[i10] + w11 * fp1[i11];
    __builtin_nontemporal_store(fcx + s0, flow_dst + fcbase + p);
    __builtin_nontemporal_store(fcy + s1, flow_dst + fcbase + HW + p);
  }

  const float* ip = iprv + (size_t)(b * LL + u) * CHW;
  const float* ic = icur + (size_t)(b * LL + t) * CHW;
  float* od = img_dst + (size_t)(b * LL + t) * CHW;
#pragma unroll 4
  for (int c = 0; c < CC; ++c) {
    const float* pl = ip + c * HW;
    // gathers stay cached (halo reuse across neighboring tiles, now same-XCD);
    // cur-read and store are pure streams -> nontemporal so they don't evict
    // the gather working set from L2.
    const float sv = w00 * pl[i00] + w01 * pl[i01] + w10 * pl[i10] + w11 * pl[i11];
    const float cv = __builtin_nontemporal_load(ic + c * HW + p);
    __builtin_nontemporal_store(cv + sv, od + c * HW + p);
  }
}

// Final locations after all steps: t=0 -> in, t=1 -> buf0, t in [2,4) -> out,
// t in [4,8) -> buf0, t in [8,32) -> out. Copy the 6 missing slices into out.
__global__ __launch_bounds__(256) void pscan_fixup(
    const float* __restrict__ img_in, const float* __restrict__ img_b0,
    float* __restrict__ img_out) {
  const int per_slice4 = (int)(BB * CHW / 4);  // float4s per copied t-slice (all b)
  int tid = blockIdx.x * blockDim.x + threadIdx.x;
  int j = tid / per_slice4;
  if (j >= 6) return;
  int e = tid % per_slice4;
  const int t = (j == 0) ? 0 : (j == 1 ? 1 : j + 2);  // 0,1,4,5,6,7
  const float* src = (j == 0) ? img_in : img_b0;
  const int b = e / (CHW / 4);
  const int rr = e % (CHW / 4);
  const size_t base = (size_t)(b * LL + t) * CHW;
  const float4* s4 = (const float4*)(src + base) + rr;
  float4* d4 = (float4*)(img_out + base) + rr;
  *d4 = *s4;
}

extern "C" void kernel_launch(void* const* d_in, const int* in_sizes, int n_in,
                              void* d_out, int out_size, void* d_ws, size_t ws_size,
                              hipStream_t stream) {
  const float* flow_in = (const float*)d_in[0];
  const float* img_in  = (const float*)d_in[1];
  float* img_out = (float*)d_out;

  float* img_b0  = (float*)d_ws;                 // 301,989,888 bytes
  float* flow_b0 = img_b0 + IMG_ELEMS;           // 37,748,736 bytes
  float* flow_b1 = flow_b0 + FLW_ELEMS;          // 37,748,736 bytes
  // total ws needed: 377,487,360 bytes

  const dim3 blk(64, 4, 1);
  const int steps[5] = {1, 2, 4, 8, 16};
  for (int i = 0; i < 5; ++i) {
    const int s = steps[i];
    const int ntt = LL - s;
    const int total_pairs = BB * ntt;
    const int ppx = (total_pairs + NXCD - 1) / NXCD;
    const dim3 grd((unsigned)(NXCD * ppx * TILES), 1, 1);
    float* idst = (s == 1 || s == 4) ? img_b0 : img_out;
    float* fdst = (s == 1 || s == 4) ? flow_b0 : flow_b1;  // unused at s=16
    pscan_step<<<grd, blk, 0, stream>>>(img_in, img_b0, img_out,
                                        flow_in, flow_b0, flow_b1,
                                        idst, fdst, s, (s < 16) ? 1 : 0,
                                        ppx, total_pairs, ntt);
  }
  const int total4 = 6 * BB * CHW / 4;  // 3,538,944 float4 copies
  pscan_fixup<<<(total4 + 255) / 256, 256, 0, stream>>>(img_in, img_b0, img_out);
}

// Round 2
// 2705.892 us; speedup vs baseline: 1.2380x; 1.0309x over previous
//
#include <hip/hip_runtime.h>

// Problem constants (from setup_inputs): B=4, L=32, C=16, H=192, W=192
#define BB 4
#define LL 32
#define CC 16
#define HH 192
#define WW 192
#define HW (HH * WW)            // 36864
#define CHW (CC * HW)           // 589824
#define FHW (2 * HW)            // 73728
#define IMG_ELEMS ((size_t)BB * LL * CHW)      // 75,497,472
#define FLW_ELEMS ((size_t)BB * LL * FHW)     // 9,437,184
#define TILES 144               // 3 across (64 wide) x 48 down (4 tall)
#define NXCD 8

typedef float f4v __attribute__((ext_vector_type(4)));
typedef float f2v __attribute__((ext_vector_type(2)));

// Location rule (q = min(s/2, msb(u)); q==0 -> original input), with NHWC
// buffers: A = NHWC input copy AND dst for q in {2,8}; B = dst for q in {1,4}.
// Aliasing is safe: s=2 writes A t>=2 (A reads only t=0 after s=1); s=8 writes
// A t>=8 (A reads only t in {0,2,3}); s=4 writes B t>=4 (B reads only t=1);
// s=16 writes img_out (NCHW) directly.
__device__ __forceinline__ bool useB_sel(int u, int shalf) {
  int q = (u > 0) ? (1 << (31 - __builtin_clz((unsigned)u))) : 0;
  q = q < shalf ? q : shalf;
  return (q == 1 || q == 4);
}

// NCHW -> NHWC conversion of the original inputs (pure copy, bit-exact).
__global__ __launch_bounds__(256) void conv_nhwc(
    const float* __restrict__ img_in, const float* __restrict__ flow_in,
    float* __restrict__ img_a, float* __restrict__ flow_a) {
  const int b = blockIdx.z, t = blockIdx.y, tile = blockIdx.x;
  const int w = (tile % 3) * 64 + threadIdx.x;
  const int h = (tile / 3) * 4 + threadIdx.y;
  const int p = h * WW + w;
  const size_t ib = (size_t)(b * LL + t) * CHW;
  float v[CC];
#pragma unroll
  for (int c = 0; c < CC; ++c)
    v[c] = __builtin_nontemporal_load(img_in + ib + c * HW + p);
  f4v* d = (f4v*)(img_a + ib + (size_t)p * CC);
#pragma unroll
  for (int k = 0; k < 4; ++k) {
    f4v x = {v[4 * k], v[4 * k + 1], v[4 * k + 2], v[4 * k + 3]};
    __builtin_nontemporal_store(x, d + k);
  }
  const size_t fb = (size_t)(b * LL + t) * FHW;
  f2v f = {__builtin_nontemporal_load(flow_in + fb + p),
           __builtin_nontemporal_load(flow_in + fb + HW + p)};
  __builtin_nontemporal_store(f, (f2v*)(flow_a + fb + 2 * p));
}

__global__ __launch_bounds__(256) void pscan_step_nhwc(
    const float* __restrict__ img_a, const float* __restrict__ img_b,
    const float* __restrict__ flow_a, const float* __restrict__ flow_b,
    float* __restrict__ img_dst, float* __restrict__ flow_dst,
    int s, int write_flow, int final_nchw,
    int pairs_per_xcd, int total_pairs, int ntt) {
  // Match the numpy f32 reference rounding-for-rounding: no FMA contraction.
  // (All weighted sums are written as explicit scalar ops inside this scope.)
#pragma clang fp contract(off)
  // XCD-affinity decode (kept from R1: FETCH_SIZE dropped 5x with it).
  const int l = blockIdx.x;
  const int xcd = l & (NXCD - 1);
  const int j = l >> 3;
  const int pair = xcd * pairs_per_xcd + j / TILES;
  if (pair >= total_pairs) return;
  const int tile = j % TILES;
  const int b = pair / ntt;
  const int t = pair % ntt + s;      // t in [s, L)
  const int u = t - s;               // source slice
  const int w = (tile % 3) * 64 + threadIdx.x;
  const int h = (tile / 3) * 4 + threadIdx.y;
  const int shalf = s >> 1;

  const bool curB = useB_sel(t, shalf), prvB = useB_sel(u, shalf);
  const float* fcur = curB ? flow_b : flow_a;
  const float* fprv = prvB ? flow_b : flow_a;
  const float* icur = curB ? img_b : img_a;
  const float* iprv = prvB ? img_b : img_a;

  const int p = h * WW + w;

  // current flow at (b,t,h,w,:) — NHWC float2, streamed once
  const size_t fcb = (size_t)(b * LL + t) * FHW;
  const f2v fc = __builtin_nontemporal_load((const f2v*)(fcur + fcb + 2 * p));
  const float fcx = fc.x, fcy = fc.y;

  // warp grid (pixel-center base grid + flow), wrap x into [-1,1)
  const float gx = (w + 0.5f) * (2.0f / WW) - 1.0f;
  const float gy = (h + 0.5f) * (2.0f / HH) - 1.0f;
  float fx = gx + fcx;
  float fy = gy + fcy;
  // np.remainder(fx+1, 2) - 1
  float r = fmodf(fx + 1.0f, 2.0f);
  if (r < 0.0f) r += 2.0f;
  fx = r - 1.0f;

  // bilinear, align_corners=False, zeros padding
  const float ix = (fx + 1.0f) * 0.5f * WW - 0.5f;
  const float iy = (fy + 1.0f) * 0.5f * HH - 0.5f;
  const float x0f = floorf(ix), y0f = floorf(iy);
  const float wx1 = ix - x0f, wy1 = iy - y0f;
  const float wx0 = 1.0f - wx1, wy0 = 1.0f - wy1;
  const int x0 = (int)x0f, y0 = (int)y0f;
  const int x1 = x0 + 1, y1 = y0 + 1;
  const bool vx0 = (x0 >= 0) & (x0 < WW), vx1 = (x1 >= 0) & (x1 < WW);
  const bool vy0 = (y0 >= 0) & (y0 < HH), vy1 = (y1 >= 0) & (y1 < HH);
  const int cx0 = min(max(x0, 0), WW - 1), cx1 = min(max(x1, 0), WW - 1);
  const int cy0 = min(max(y0, 0), HH - 1), cy1 = min(max(y1, 0), HH - 1);
  const float w00 = wy0 * wx0 * ((vy0 && vx0) ? 1.0f : 0.0f);
  const float w01 = wy0 * wx1 * ((vy0 && vx1) ? 1.0f : 0.0f);
  const float w10 = wy1 * wx0 * ((vy1 && vx0) ? 1.0f : 0.0f);
  const float w11 = wy1 * wx1 * ((vy1 && vx1) ? 1.0f : 0.0f);
  const int i00 = cy0 * WW + cx0, i01 = cy0 * WW + cx1;
  const int i10 = cy1 * WW + cx0, i11 = cy1 * WW + cx1;

  if (write_flow) {
    const float* fpb = fprv + (size_t)(b * LL + u) * FHW;
    const f2v g00 = *(const f2v*)(fpb + 2 * i00);
    const f2v g01 = *(const f2v*)(fpb + 2 * i01);
    const f2v g10 = *(const f2v*)(fpb + 2 * i10);
    const f2v g11 = *(const f2v*)(fpb + 2 * i11);
    const float s0 = w00 * g00.x + w01 * g01.x + w10 * g10.x + w11 * g11.x;
    const float s1 = w00 * g00.y + w01 * g01.y + w10 * g10.y + w11 * g11.y;
    f2v o = {fcx + s0, fcy + s1};
    __builtin_nontemporal_store(o, (f2v*)(flow_dst + fcb + 2 * p));
  }

  // image: NHWC gather — one pixel-tap = one 64B line (16 ch * 4B)
  const float* ipb = iprv + (size_t)(b * LL + u) * CHW;
  const f4v* t00 = (const f4v*)(ipb + (size_t)i00 * CC);
  const f4v* t01 = (const f4v*)(ipb + (size_t)i01 * CC);
  const f4v* t10 = (const f4v*)(ipb + (size_t)i10 * CC);
  const f4v* t11 = (const f4v*)(ipb + (size_t)i11 * CC);
  const f4v* icp = (const f4v*)(icur + (size_t)(b * LL + t) * CHW + (size_t)p * CC);

  if (!final_nchw) {
    f4v* odp = (f4v*)(img_dst + (size_t)(b * LL + t) * CHW + (size_t)p * CC);
#pragma unroll
    for (int k = 0; k < 4; ++k) {
      const f4v a = t00[k], e = t01[k], c = t10[k], d = t11[k];
      const f4v cv = __builtin_nontemporal_load(icp + k);
      f4v o;
      {
        const float s0 = w00 * a.x + w01 * e.x + w10 * c.x + w11 * d.x;
        const float s1 = w00 * a.y + w01 * e.y + w10 * c.y + w11 * d.y;
        const float s2 = w00 * a.z + w01 * e.z + w10 * c.z + w11 * d.z;
        const float s3 = w00 * a.w + w01 * e.w + w10 * c.w + w11 * d.w;
        o.x = cv.x + s0; o.y = cv.y + s1; o.z = cv.z + s2; o.w = cv.w + s3;
      }
      __builtin_nontemporal_store(o, odp + k);
    }
  } else {
    // final step (s=16): write NCHW directly into the output buffer;
    // per-channel scalar stores are coalesced across the wave's 64 lanes.
    float* od = img_dst + (size_t)(b * LL + t) * CHW;
#pragma unroll
    for (int k = 0; k < 4; ++k) {
      const f4v a = t00[k], e = t01[k], c = t10[k], d = t11[k];
      const f4v cv = __builtin_nontemporal_load(icp + k);
      const float s0 = w00 * a.x + w01 * e.x + w10 * c.x + w11 * d.x;
      const float s1 = w00 * a.y + w01 * e.y + w10 * c.y + w11 * d.y;
      const float s2 = w00 * a.z + w01 * e.z + w10 * c.z + w11 * d.z;
      const float s3 = w00 * a.w + w01 * e.w + w10 * c.w + w11 * d.w;
      __builtin_nontemporal_store(cv.x + s0, od + (4 * k + 0) * HW + p);
      __builtin_nontemporal_store(cv.y + s1, od + (4 * k + 1) * HW + p);
      __builtin_nontemporal_store(cv.z + s2, od + (4 * k + 2) * HW + p);
      __builtin_nontemporal_store(cv.w + s3, od + (4 * k + 3) * HW + p);
    }
  }
}

// t=0 is never updated: plain NCHW copy from the input.
__global__ __launch_bounds__(256) void fixup_t0(const float* __restrict__ img_in,
                                                float* __restrict__ img_out) {
  const int per_b = CHW / 4;
  int idx = blockIdx.x * blockDim.x + threadIdx.x;
  if (idx >= BB * per_b) return;
  const int b = idx / per_b, rr = idx % per_b;
  const size_t base = (size_t)(b * LL) * CHW;
  ((f4v*)(img_out + base))[rr] = ((const f4v*)(img_in + base))[rr];
}

// Final locations: t=1 -> B(q1), t in [2,4) -> A(q2), t in [4,8) -> B(q4),
// t in [8,16) -> A(q8); all NHWC -> transpose into NCHW output.
// t in [16,32) was written NCHW by the s=16 step.
__global__ __launch_bounds__(256) void fixup_tr(const float* __restrict__ img_a,
                                                const float* __restrict__ img_b,
                                                float* __restrict__ img_out) {
  const int b = blockIdx.z;
  const int t = blockIdx.y + 1;            // 1..15
  const int tile = blockIdx.x;
  const int w = (tile % 3) * 64 + threadIdx.x;
  const int h = (tile / 3) * 4 + threadIdx.y;
  const int p = h * WW + w;
  const bool useB = (t == 1) || (t >= 4 && t < 8);
  const float* src = useB ? img_b : img_a;
  const size_t base = (size_t)(b * LL + t) * CHW;
  const f4v* sp = (const f4v*)(src + base + (size_t)p * CC);
  float* od = img_out + base;
#pragma unroll
  for (int k = 0; k < 4; ++k) {
    const f4v v = __builtin_nontemporal_load(sp + k);
    __builtin_nontemporal_store(v.x, od + (4 * k + 0) * HW + p);
    __builtin_nontemporal_store(v.y, od + (4 * k + 1) * HW + p);
    __builtin_nontemporal_store(v.z, od + (4 * k + 2) * HW + p);
    __builtin_nontemporal_store(v.w, od + (4 * k + 3) * HW + p);
  }
}

extern "C" void kernel_launch(void* const* d_in, const int* in_sizes, int n_in,
                              void* d_out, int out_size, void* d_ws, size_t ws_size,
                              hipStream_t stream) {
  const float* flow_in = (const float*)d_in[0];
  const float* img_in  = (const float*)d_in[1];
  float* img_out = (float*)d_out;

  float* img_a  = (float*)d_ws;            // NHWC input copy + dst{2,8}: 301,989,888 B
  float* img_b  = img_a + IMG_ELEMS;       // dst{1,4}: 301,989,888 B
  float* flow_a = img_b + IMG_ELEMS;       // NHWC flow input + fdst{2,8}: 37,748,736 B
  float* flow_b = flow_a + FLW_ELEMS;      // fdst{1,4}: 37,748,736 B
  // total ws needed: 679,477,248 bytes

  const dim3 blk(64, 4, 1);
  conv_nhwc<<<dim3(TILES, LL, BB), blk, 0, stream>>>(img_in, flow_in, img_a, flow_a);

  const int steps[5] = {1, 2, 4, 8, 16};
  for (int i = 0; i < 5; ++i) {
    const int s = steps[i];
    const int ntt = LL - s;
    const int total_pairs = BB * ntt;
    const int ppx = (total_pairs + NXCD - 1) / NXCD;
    const dim3 grd((unsigned)(NXCD * ppx * TILES), 1, 1);
    float* idst = (s == 16) ? img_out : ((s == 1 || s == 4) ? img_b : img_a);
    float* fdst = (s == 1 || s == 4) ? flow_b : flow_a;  // unused at s=16
    pscan_step_nhwc<<<grd, blk, 0, stream>>>(img_a, img_b, flow_a, flow_b,
                                             idst, fdst, s, (s < 16) ? 1 : 0,
                                             (s == 16) ? 1 : 0,
                                             ppx, total_pairs, ntt);
  }
  fixup_t0<<<(BB * (CHW / 4) + 255) / 256, 256, 0, stream>>>(img_in, img_out);
  fixup_tr<<<dim3(TILES, 15, BB), blk, 0, stream>>>(img_a, img_b, img_out);
}